// Round 3
// baseline (7196.966 us; speedup 1.0000x reference)
//
#include <hip/hip_runtime.h>
#include <cstdint>
#include <cstddef>

// AttentiveFP forward. B=256 L=128 K=6 FA=39 FB=10 D=128 R=3 T=2.
// ALL float tensors are float32 (per reference); indices int32.
// ws usage: one fp32 h buffer [B*L*D] = 16 MB. h ping-pongs ws <-> d_out.

#define B_ 256
#define L_ 128
#define K_ 6
#define FA_ 39
#define FB_ 10
#define D_ 128
#define PAD_ 127
#define NEGC (-9.0e8f)

__device__ __forceinline__ float lrelu(float x) { return x > 0.f ? x : 0.01f * x; }
__device__ __forceinline__ float eluf(float x)  { return x > 0.f ? x : expm1f(x); }
__device__ __forceinline__ float sigm(float x)  { return 1.f / (1.f + expf(-x)); }

// acc + dot(w_row[0:128], x[0:128]); w_row contiguous fp32, 16B-aligned.
__device__ __forceinline__ float dot128(const float* __restrict__ w,
                                        const float* __restrict__ x, float acc) {
  const float4* wp = (const float4*)w;
#pragma unroll
  for (int i = 0; i < 32; i++) {
    float4 u = wp[i];
    acc += x[4 * i + 0] * u.x + x[4 * i + 1] * u.y
         + x[4 * i + 2] * u.z + x[4 * i + 3] * u.w;
  }
  return acc;
}

// 128-thread block reductions. Safe for immediate reuse of `red`.
__device__ __forceinline__ float blk_sum(float v, float* red, int tid) {
  red[tid] = v; __syncthreads();
  for (int s = 64; s > 0; s >>= 1) {
    if (tid < s) red[tid] += red[tid + s];
    __syncthreads();
  }
  float r = red[0]; __syncthreads();
  return r;
}
__device__ __forceinline__ float blk_max(float v, float* red, int tid) {
  red[tid] = v; __syncthreads();
  for (int s = 64; s > 0; s >>= 1) {
    if (tid < s) red[tid] = fmaxf(red[tid], red[tid + s]);
    __syncthreads();
  }
  float r = red[0]; __syncthreads();
  return r;
}

__global__ __launch_bounds__(128) void k_round(
    int first,
    const float* __restrict__ hin,    // h from prev round (null if first)
    float* __restrict__ hout,         // h out
    const float* __restrict__ atom_list,
    const float* __restrict__ bond_list,
    const int* __restrict__ adeg,
    const int* __restrict__ bdeg,
    const float* __restrict__ afc_w, const float* __restrict__ afc_b,
    const float* __restrict__ nbr_w, const float* __restrict__ nbr_b,
    const float* __restrict__ aw, const float* __restrict__ ab,
    const float* __restrict__ tw, const float* __restrict__ tb,
    const float* __restrict__ wih, const float* __restrict__ whh,
    const float* __restrict__ bih, const float* __restrict__ bhh)
{
  int a = blockIdx.x;       // global atom id
  int bb = a >> 7;          // molecule
  int tid = threadIdx.x;

  __shared__ float cur[D_], hrow[D_], nbr[K_][D_], ybar[D_], ctx[D_], red[D_];
  __shared__ float sK[K_];
  __shared__ float xa[FA_];
  __shared__ float xc[FA_ + FB_];
  __shared__ int aidx[K_], bidx[K_];

  if (tid < K_) { aidx[tid] = adeg[a * K_ + tid]; bidx[tid] = bdeg[a * K_ + tid]; }

  if (first) {
    // atom_feature = lrelu(atom_list @ afc_w + afc_b) for own atom
    if (tid < FA_) xa[tid] = atom_list[(size_t)a * FA_ + tid];
    __syncthreads();
    float acc = afc_b[tid];
    for (int j = 0; j < FA_; j++) acc += xa[j] * afc_w[j * D_ + tid];
    float hv = lrelu(acc);
    hrow[tid] = hv;
    cur[tid] = hv;
    __syncthreads();
    // neighbor features: lrelu(concat(atom, bond) @ nbr_w + nbr_b)
    for (int k = 0; k < K_; k++) {
      int an = aidx[k], bn = bidx[k];
      if (tid < FA_)
        xc[tid] = atom_list[(size_t)(bb * L_ + an) * FA_ + tid];
      else if (tid < FA_ + FB_)
        xc[tid] = bond_list[(size_t)(bb * L_ + bn) * FB_ + (tid - FA_)];
      __syncthreads();
      float na = nbr_b[tid];
      for (int j = 0; j < FA_ + FB_; j++) na += xc[j] * nbr_w[j * D_ + tid];
      nbr[k][tid] = lrelu(na);
      __syncthreads();
    }
  } else {
    float hv = hin[(size_t)a * D_ + tid];
    hrow[tid] = hv;
    cur[tid] = fmaxf(hv, 0.f);   // act = relu(h)
    __syncthreads();
    for (int k = 0; k < K_; k++) {
      int an = aidx[k];
      nbr[k][tid] = fmaxf(hin[(size_t)(bb * L_ + an) * D_ + tid], 0.f);
    }
    __syncthreads();
  }

  // scores: s_k = dot(cur, aw[0:D]) + dot(nbr_k, aw[D:2D])
  float awlo = aw[tid];
  float awhi = aw[D_ + tid];
  float caw = cur[tid] * awlo;
  for (int k = 0; k < K_; k++) {
    float s = blk_sum(caw + nbr[k][tid] * awhi, red, tid);
    if (tid == 0) sK[k] = s;
  }
  __syncthreads();

  // softmax over K (computed redundantly per thread; all inputs uniform)
  float abv = ab[0];
  float sc[K_], wk[K_];
  float m = -3.0e38f;
  for (int k = 0; k < K_; k++) {
    float s = lrelu(sK[k] + abv);
    if (aidx[k] == PAD_) s += NEGC;
    sc[k] = s;
    m = fmaxf(m, s);
  }
  float es = 0.f;
  for (int k = 0; k < K_; k++) { sc[k] = expf(sc[k] - m); es += sc[k]; }
  float wsum = 0.f;
  for (int k = 0; k < K_; k++) {
    float w = (aidx[k] == PAD_) ? 0.f : sc[k] / es;
    wk[k] = w; wsum += w;
  }

  // ybar = sum_k w_k * nbr_k ; ctx = elu(ybar @ tw + wsum * tb)
  float yb = 0.f;
  for (int k = 0; k < K_; k++) yb += wk[k] * nbr[k][tid];
  ybar[tid] = yb;
  __syncthreads();
  float acc = wsum * tb[tid];
  for (int j = 0; j < D_; j++) acc += ybar[j] * tw[j * D_ + tid];
  ctx[tid] = eluf(acc);
  __syncthreads();

  // GRUCell
  float gi[3], gh[3];
#pragma unroll
  for (int c = 0; c < 3; c++) {
    int g = c * D_ + tid;
    gi[c] = dot128(wih + (size_t)g * D_, ctx,  bih[g]);
    gh[c] = dot128(whh + (size_t)g * D_, hrow, bhh[g]);
  }
  float r = sigm(gi[0] + gh[0]);
  float z = sigm(gi[1] + gh[1]);
  float n = tanhf(gi[2] + r * gh[2]);
  float hv = hrow[tid];
  float hn = (1.f - z) * n + z * hv;

  hout[(size_t)a * D_ + tid] = hn;
}

__global__ __launch_bounds__(128) void k_mol(
    const float* __restrict__ hfin,   // final h (ws)
    float* __restrict__ hcopy,        // d_out h region — copy of final h
    const float* __restrict__ amask,
    const float* __restrict__ maw, const float* __restrict__ mab,
    const float* __restrict__ mtw, const float* __restrict__ mtb,
    const float* __restrict__ wih, const float* __restrict__ whh,
    const float* __restrict__ bih, const float* __restrict__ bhh,
    const float* __restrict__ ow, const float* __restrict__ ob,
    float* __restrict__ pred)
{
  int b = blockIdx.x;
  int tid = threadIdx.x;
  __shared__ float actS[L_][D_ + 1];   // relu(h), padded vs bank conflicts
  __shared__ float red[D_], wgt[L_], ybv[D_], ctx[D_], mfS[D_], amol[D_];
  __shared__ float msk[L_], mawh[D_];

  msk[tid] = amask[b * L_ + tid];
  mawh[tid] = maw[D_ + tid];
  for (int l = 0; l < L_; l++) {
    float hv = hfin[(size_t)(b * L_ + l) * D_ + tid];
    hcopy[(size_t)(b * L_ + l) * D_ + tid] = hv;   // emit final h output
    actS[l][tid] = fmaxf(hv, 0.f);
  }
  __syncthreads();

  // mol_feature = sum_l act_l * mask_l
  float mf = 0.f;
  for (int l = 0; l < L_; l++) mf += actS[l][tid] * msk[l];
  mfS[tid] = mf;
  amol[tid] = fmaxf(mf, 0.f);
  __syncthreads();

  float mabv = mab[0];

  for (int t = 0; t < 2; t++) {
    // s0 = dot(act_mol, maw[0:D]) — shared by all atoms
    float s0 = blk_sum(amol[tid] * maw[tid], red, tid);

    // score for atom l = tid
    float sc = s0 + mabv;
    for (int j = 0; j < D_; j++) sc += actS[tid][j] * mawh[j];
    sc = lrelu(sc);
    if (msk[tid] == 0.f) sc += NEGC;

    // softmax over atoms
    float mx = blk_max(sc, red, tid);
    float e = expf(sc - mx);
    float es = blk_sum(e, red, tid);
    float w = (e / es) * msk[tid];
    wgt[tid] = w;
    float wsum = blk_sum(w, red, tid);
    __syncthreads();

    // y = sum_l w_l * act_l ; ctx = elu(y @ mtw + wsum * mtb)
    float y = 0.f;
    for (int l = 0; l < L_; l++) y += wgt[l] * actS[l][tid];
    ybv[tid] = y;
    __syncthreads();
    float acc = wsum * mtb[tid];
    for (int j = 0; j < D_; j++) acc += ybv[j] * mtw[j * D_ + tid];
    ctx[tid] = eluf(acc);
    __syncthreads();

    // GRUCell on mol_feature
    float gi[3], gh[3];
#pragma unroll
    for (int c = 0; c < 3; c++) {
      int g = c * D_ + tid;
      gi[c] = dot128(wih + (size_t)g * D_, ctx, bih[g]);
      gh[c] = dot128(whh + (size_t)g * D_, mfS, bhh[g]);
    }
    float r = sigm(gi[0] + gh[0]);
    float z = sigm(gi[1] + gh[1]);
    float n = tanhf(gi[2] + r * gh[2]);
    float hn = (1.f - z) * n + z * mfS[tid];
    __syncthreads();
    mfS[tid] = hn;
    amol[tid] = fmaxf(hn, 0.f);
    __syncthreads();
  }

  float p = blk_sum(mfS[tid] * ow[tid], red, tid);
  if (tid == 0) pred[b] = p + ob[0];
}

extern "C" void kernel_launch(void* const* d_in, const int* in_sizes, int n_in,
                              void* d_out, int out_size, void* d_ws, size_t ws_size,
                              hipStream_t stream) {
  const float* atom_list    = (const float*)d_in[0];
  const float* bond_list    = (const float*)d_in[1];
  const float* atom_mask    = (const float*)d_in[2];
  const float* atom_fc_w    = (const float*)d_in[3];
  const float* atom_fc_b    = (const float*)d_in[4];
  const float* nbr_fc_w     = (const float*)d_in[5];
  const float* nbr_fc_b     = (const float*)d_in[6];
  const float* align_w      = (const float*)d_in[7];
  const float* align_b      = (const float*)d_in[8];
  const float* attend_w     = (const float*)d_in[9];
  const float* attend_b     = (const float*)d_in[10];
  const float* gru_wih      = (const float*)d_in[11];
  const float* gru_whh      = (const float*)d_in[12];
  const float* gru_bih      = (const float*)d_in[13];
  const float* gru_bhh      = (const float*)d_in[14];
  const float* mol_align_w  = (const float*)d_in[15];
  const float* mol_align_b  = (const float*)d_in[16];
  const float* mol_attend_w = (const float*)d_in[17];
  const float* mol_attend_b = (const float*)d_in[18];
  const float* mol_gru_wih  = (const float*)d_in[19];
  const float* mol_gru_whh  = (const float*)d_in[20];
  const float* mol_gru_bih  = (const float*)d_in[21];
  const float* mol_gru_bhh  = (const float*)d_in[22];
  const float* out_w        = (const float*)d_in[23];
  const float* out_b        = (const float*)d_in[24];
  const int*   adeg         = (const int*)d_in[25];
  const int*   bdeg         = (const int*)d_in[26];

  const size_t NH = (size_t)B_ * L_ * D_;
  float* hW   = (float*)d_ws;            // 16 MB scratch h
  float* hOut = (float*)d_out;           // h region of output
  float* pred = hOut + NH;               // [B]

  dim3 blk(128), grd(B_ * L_);

  // r0 -> hW ; r1: hW -> hOut ; r2: hOut -> hW ; k_mol: hW -> (hOut copy, pred)
  const float* rin[3]  = { nullptr, hW, hOut };
  float*       rout[3] = { hW, hOut, hW };
  for (int d = 0; d < 3; d++) {
    hipLaunchKernelGGL(k_round, grd, blk, 0, stream,
        (d == 0) ? 1 : 0, rin[d], rout[d],
        atom_list, bond_list, adeg, bdeg,
        atom_fc_w, atom_fc_b, nbr_fc_w, nbr_fc_b,
        align_w + (size_t)d * 2 * D_, align_b + d,
        attend_w + (size_t)d * D_ * D_, attend_b + (size_t)d * D_,
        gru_wih + (size_t)d * 3 * D_ * D_, gru_whh + (size_t)d * 3 * D_ * D_,
        gru_bih + (size_t)d * 3 * D_, gru_bhh + (size_t)d * 3 * D_);
  }

  hipLaunchKernelGGL(k_mol, dim3(B_), blk, 0, stream,
      hW, hOut, atom_mask, mol_align_w, mol_align_b, mol_attend_w, mol_attend_b,
      mol_gru_wih, mol_gru_whh, mol_gru_bih, mol_gru_bhh, out_w, out_b, pred);
}